// Round 7
// baseline (2247.978 us; speedup 1.0000x reference)
//
#include <hip/hip_runtime.h>
#include <hip/hip_bf16.h>

// Problem constants (from reference): B=64, NCLS=200 -> BN rows = 12800
#define BROWS  12800
#define TSTEPS 8
#define EMB    300
#define EMBP   320          // EMB padded to /32, x-slot width
#define RNN    512
#define NG     2048         // 4*RNN gate width
#define K1     832          // EMBP + RNN  (layer-1 concat GEMM K), 13*64
#define K2     1024         // RNN + RNN   (layer-2 concat GEMM K), 16*64

typedef short bf16x8 __attribute__((ext_vector_type(8)));   // 8 bf16 in 4 VGPRs (m89-verified operand type)
typedef float f32x4  __attribute__((ext_vector_type(4)));
typedef __hip_bfloat16 bf16;

__device__ __forceinline__ float sigmoidf_(float x) { return 1.f / (1.f + __expf(-x)); }
// exp-based tanh: exact saturation at +-inf, ~ulp-level error vs tanhf, one v_exp
__device__ __forceinline__ float tanhf_(float x)    { return 1.f - 2.f / (__expf(2.f * x) + 1.f); }

// async global->LDS, 16B per lane (m97). LDS dest = wave-uniform base + lane*16.
__device__ __forceinline__ void gl_lds16(const bf16* g, bf16* l) {
    __builtin_amdgcn_global_load_lds(
        (const __attribute__((address_space(1))) void*)g,
        (__attribute__((address_space(3))) void*)l,
        16, 0, 0);
}

// ---------------------------------------------------------------------------
// Weight repack (round-3 proven): fp32 -> bf16, K-concat LINEAR row-major
// [N=2048][K], GATE-INTERLEAVED row permutation: output row n encodes
//   w = n&15 (unit), g = (n>>4)&3 (gate i,f,g,o), b = n>>6 (unit group)
//   original row = g*512 + b*16 + w
// => each wave's 64-col span = [i|f|g|o] of the same 16 units (epilogue needs
// no cross-lane exchange). Emits permuted combined biases Bp = bih+bhh.
// ---------------------------------------------------------------------------
__global__ void convert_weights(const float* __restrict__ Wih1, const float* __restrict__ Whh1,
                                const float* __restrict__ Wih2, const float* __restrict__ Whh2,
                                const float* __restrict__ bih1, const float* __restrict__ bhh1,
                                const float* __restrict__ bih2, const float* __restrict__ bhh2,
                                bf16* __restrict__ Wc1, bf16* __restrict__ Wc2,
                                float* __restrict__ Bp1, float* __restrict__ Bp2) {
    int idx = blockIdx.x * 256 + threadIdx.x;
    const int n1 = NG * K1;   // 1,703,936
    const int n2 = NG * K2;   // 2,097,152
    if (idx < n1) {
        int n = idx / K1, k = idx - n * K1;
        int on = ((n >> 4) & 3) * RNN + (n >> 6) * 16 + (n & 15);
        float v = 0.f;
        if (k < EMB)        v = Wih1[on * EMB + k];
        else if (k >= EMBP) v = Whh1[on * RNN + (k - EMBP)];
        Wc1[idx] = __float2bfloat16(v);
    }
    if (idx < n2) {
        int n = idx >> 10, k = idx & (K2 - 1);
        int on = ((n >> 4) & 3) * RNN + (n >> 6) * 16 + (n & 15);
        float v = (k < RNN) ? Wih2[on * RNN + k] : Whh2[on * RNN + (k - RNN)];
        Wc2[idx] = __float2bfloat16(v);
    }
    if (idx < NG) {
        int on = ((idx >> 4) & 3) * RNN + (idx >> 6) * 16 + (idx & 15);
        Bp1[idx] = bih1[on] + bhh1[on];
        Bp2[idx] = bih2[on] + bhh2[on];
    }
}

// ---------------------------------------------------------------------------
// Embedding gather + tanh -> Xbuf [BROWS][320] (cols 300..319 zero pad).
// Written before layer-1 reads it each step; nothing else touches it.
// ---------------------------------------------------------------------------
__global__ void embed_step(const int* __restrict__ sent, const float* __restrict__ w2v,
                           bf16* __restrict__ Xbuf, int t) {
    int row = blockIdx.x;
    int col = threadIdx.x;                 // 0..319
    int id  = sent[row * TSTEPS + t];
    float v = (col < EMB) ? tanhf_(w2v[id * EMB + col]) : 0.f;
    Xbuf[(size_t)row * EMBP + col] = __float2bfloat16(v);
}

// ---------------------------------------------------------------------------
// Fused GEMM + LSTM cell update (round-3 core, RACE-FREE dataflow).
//   gates[M,2048] = A[M,K] * W[2048,K]^T  (bf16 MFMA 16x16x32, fp32 acc)
// A is a virtual K-concat of two sources:
//   k <  ksplit : Ax (row stride ldx)      — layer-1 x_t, layer-2 unused
//   k >= ksplit : Ah (row stride ldh_in)   — h columns from the PREVIOUS
//                                            dispatch's buffer (ping-pong)
// The write target hdst is always the OTHER A2 buffer => no dispatch ever
// reads and writes the same buffer (round-6's race is structurally gone).
//
// Staging: both operands via global_load_lds w=16 (rounds 4&5 proved direct
// global fragment loads are latency-bound losers). LDS unpadded [128][64]
// with XOR chunk swizzle on the global side (zero bank conflicts, round-3).
// Epilogue: per (row,unit) c'=sig(f)*c+sig(i)*tanh(g); h=sig(o)*tanh(c');
// weight permutation puts gates i,f,g,o of one (row,unit) in one thread.
// h routed through LDS transpose (stride 40: q-groups hit bank sets
// {0..7},{16..23},{0..7},{16..23} -> 2-way only = free per m136) for
// full-line coalesced global stores.
// Block 256 thr = 4 waves; tile 128x128; wave 64x64 = 4x4 MFMA tiles.
// Grid (16,100), bn fastest => same-bm blocks dispatch-adjacent (L2 sharing
// of A row-slices; round-6 showed breaking this adjacency costs ~2x).
// ---------------------------------------------------------------------------
#define BM 128
#define BN 128

__global__ __launch_bounds__(256, 5) void gemm_lstm(const bf16* __restrict__ Ax, int ldx, int ksplit,
                                                    const bf16* __restrict__ Ah, int ldh_in,
                                                    const bf16* __restrict__ W,
                                                    const float* __restrict__ Bp,
                                                    float* __restrict__ cst,
                                                    bf16* __restrict__ hdst, int ldh_out, int offh,
                                                    float* __restrict__ outf, int en_out,
                                                    int K) {
    __shared__ __attribute__((aligned(16))) bf16 sA[BM * 64];   // 16 KB (reused as h xpose buf)
    __shared__ __attribute__((aligned(16))) bf16 sB[BN * 64];   // 16 KB

    const int tid  = threadIdx.x;
    const int lane = tid & 63;
    const int wave = tid >> 6;
    const int wm   = wave >> 1, wn = wave & 1;
    const int bn   = blockIdx.x;           // 16  (gate-col blocks, fastest)
    const int bm   = blockIdx.y;           // 100 (row blocks)

    f32x4 acc[4][4];
#pragma unroll
    for (int i = 0; i < 4; ++i)
#pragma unroll
        for (int j = 0; j < 4; ++j)
#pragma unroll
            for (int r = 0; r < 4; ++r) acc[i][j][r] = 0.f;

    const int r = lane & 15, q = lane >> 4;

    // staging geometry: chunk ch = c*256+tid; row = ch>>3;
    // global k-chunk = (ch&7)^(row&7)  (XOR swizzle, zero conflicts)
    int srow[4], scol[4];
#pragma unroll
    for (int c = 0; c < 4; ++c) {
        int ch = c * 256 + tid;
        srow[c] = ch >> 3;
        scol[c] = ((ch & 7) ^ (srow[c] & 7)) * 8;
    }
    const bf16* Wbase = W + (size_t)(bn * BN) * K;

    for (int kb = 0; kb < K; kb += 64) {
        // wave-uniform source select (x-region vs h-region of the virtual A)
        const bf16* src; int ld, ko;
        if (kb < ksplit) { src = Ax; ld = ldx;    ko = kb; }
        else             { src = Ah; ld = ldh_in; ko = kb - ksplit; }
        src += (size_t)(bm * BM) * ld;
#pragma unroll
        for (int c = 0; c < 4; ++c) {
            int ch = c * 256 + tid;
            gl_lds16(src   + (size_t)srow[c] * ld + ko + scol[c], &sA[ch * 8]);
            gl_lds16(Wbase + (size_t)srow[c] * K  + kb + scol[c], &sB[ch * 8]);
        }
        __syncthreads();
#pragma unroll
        for (int kk = 0; kk < 64; kk += 32) {
            const int kc = kk >> 3;        // 0 or 4
            bf16x8 af[4], wf[4];
#pragma unroll
            for (int i = 0; i < 4; ++i)
                af[i] = *(const bf16x8*)(&sA[(wm * 64 + i * 16 + r) * 64 + (((q + kc) ^ (r & 7)) * 8)]);
#pragma unroll
            for (int j = 0; j < 4; ++j)
                wf[j] = *(const bf16x8*)(&sB[(wn * 64 + j * 16 + r) * 64 + (((q + kc) ^ (r & 7)) * 8)]);
#pragma unroll
            for (int i = 0; i < 4; ++i)
#pragma unroll
                for (int j = 0; j < 4; ++j)
                    acc[i][j] = __builtin_amdgcn_mfma_f32_16x16x32_bf16(
                        af[i], wf[j], acc[i][j], 0, 0, 0);
        }
        __syncthreads();
    }
    // trailing barrier: all sA reads done -> safe to reuse as h buffer

    // ---- fused LSTM epilogue ----
    // C/D mapping (m89/m91-verified): col = lane&15, row = (lane>>4)*4 + reg
    const int colb = bn * BN + wn * 64;
    const int u    = (2 * bn + wn) * 16 + r;      // global unit index 0..511
    const float bi = Bp[colb + r];
    const float bf = Bp[colb + 16 + r];
    const float bg = Bp[colb + 32 + r];
    const float bo = Bp[colb + 48 + r];

    // hoist the 16 c-loads so their latency overlaps the math below
    float cc[4][4];
#pragma unroll
    for (int i = 0; i < 4; ++i)
#pragma unroll
        for (int rr = 0; rr < 4; ++rr) {
            int row = bm * BM + wm * 64 + i * 16 + q * 4 + rr;
            cc[i][rr] = cst[(size_t)row * RNN + u];
        }

#define HLD 40   // h-xpose row stride: 80B rows (16B-aligned); q-group bank
                 // offsets {0,16,0,16} -> 2-way aliasing only (free, m136)
#pragma unroll
    for (int i = 0; i < 4; ++i) {
#pragma unroll
        for (int rr = 0; rr < 4; ++rr) {
            int rowl = wm * 64 + i * 16 + q * 4 + rr;       // row in block
            int row  = bm * BM + rowl;
            size_t cidx = (size_t)row * RNN + u;
            float gi = acc[i][0][rr] + bi;
            float gf = acc[i][1][rr] + bf;
            float gg = acc[i][2][rr] + bg;
            float go = acc[i][3][rr] + bo;
            float cn = sigmoidf_(gf) * cc[i][rr] + sigmoidf_(gi) * tanhf_(gg);
            float h  = sigmoidf_(go) * tanhf_(cn);
            cst[cidx] = cn;                                  // 64B segments
            if (en_out) outf[cidx] = h;
            sA[rowl * HLD + wn * 16 + r] = __float2bfloat16(h);
        }
    }
    __syncthreads();

    // coalesced h stores: 128 rows x 32 units bf16; 16B x 512 chunks
#pragma unroll
    for (int half = 0; half < 2; ++half) {
        int t    = half * 256 + tid;       // 0..511
        int rowl = t >> 2;                 // 0..127
        int c8   = (t & 3) * 8;            // 0,8,16,24
        uint4 v  = *(const uint4*)&sA[rowl * HLD + c8];
        int row  = bm * BM + rowl;
        int gcol = bn * 32 + c8;           // unit col within [0,512)
        *(uint4*)&hdst[(size_t)row * ldh_out + offh + gcol] = v;
    }
#undef HLD
}

// ---------------------------------------------------------------------------
// Workspace layout (all 16B-aligned; total 120,668,160 B):
//   c1   fp32 [12800][512]           26,214,400   offset 0
//   c2   fp32 [12800][512]           26,214,400   offset  26,214,400
//   A2a  bf16 [12800][1024]          26,214,400   offset  52,428,800
//   A2b  bf16 [12800][1024]          26,214,400   offset  78,643,200
//   Xbuf bf16 [12800][320]            8,192,000   offset 104,857,600
//   Wc1  bf16 [2048][832]             3,407,872   offset 113,049,600
//   Wc2  bf16 [2048][1024]            4,194,304   offset 116,457,472
//   Bp1  fp32 [2048]                      8,192   offset 120,651,776
//   Bp2  fp32 [2048]                      8,192   offset 120,659,968
// First 104,857,600 B (c1,c2,A2a,A2b) zeroed each call: c(-1)=0, h1(-1)=0
// (A2b cols[0,512) read at t=0), h2(-1)=0 (A2a cols[512,1024) read at t=0).
// Ping-pong: cur = t&1 (A2a at even t). L1(t): reads A2[!cur][0,512)=h1(t-1),
// writes h1(t)->A2[cur][0,512). L2(t): reads A2[cur]=[h1(t)|h2(t-1)], writes
// h2(t)->A2[!cur][512,1024). No dispatch reads and writes the same buffer.
// ---------------------------------------------------------------------------
extern "C" void kernel_launch(void* const* d_in, const int* in_sizes, int n_in,
                              void* d_out, int out_size, void* d_ws, size_t ws_size,
                              hipStream_t stream) {
    (void)in_sizes; (void)n_in; (void)out_size; (void)ws_size;
    const int*   sent = (const int*)d_in[0];
    const float* w2v  = (const float*)d_in[1];
    const float* Wih1 = (const float*)d_in[2];
    const float* Whh1 = (const float*)d_in[3];
    const float* bih1 = (const float*)d_in[4];
    const float* bhh1 = (const float*)d_in[5];
    const float* Wih2 = (const float*)d_in[6];
    const float* Whh2 = (const float*)d_in[7];
    const float* bih2 = (const float*)d_in[8];
    const float* bhh2 = (const float*)d_in[9];
    float* out = (float*)d_out;

    char* ws = (char*)d_ws;
    float* c1   = (float*)(ws);
    float* c2   = (float*)(ws + 26214400);
    bf16*  A2[2];
    A2[0] = (bf16*)(ws + 52428800);
    A2[1] = (bf16*)(ws + 78643200);
    bf16*  Xbuf = (bf16*) (ws + 104857600);
    bf16*  Wc1  = (bf16*) (ws + 113049600);
    bf16*  Wc2  = (bf16*) (ws + 116457472);
    float* Bp1  = (float*)(ws + 120651776);
    float* Bp2  = (float*)(ws + 120659968);

    // zero c1,c2,A2a,A2b (ws is re-poisoned 0xAA before every call)
    hipMemsetAsync(ws, 0, 104857600, stream);

    convert_weights<<<dim3((NG * K2 + 255) / 256), dim3(256), 0, stream>>>(
        Wih1, Whh1, Wih2, Whh2, bih1, bhh1, bih2, bhh2, Wc1, Wc2, Bp1, Bp2);

    for (int t = 0; t < TSTEPS; ++t) {
        const int cur = t & 1, prv = cur ^ 1;

        // x_t -> Xbuf (cols 300..319 zeroed)
        embed_step<<<dim3(BROWS), dim3(EMBP), 0, stream>>>(sent, w2v, Xbuf, t);

        // layer 1: gates = [x_t | h1(t-1)] @ Wc1^T, fused update
        //   x from Xbuf (stride 320), h1(t-1) from A2[prv] cols [0,512)
        //   h1(t) -> A2[cur] cols [0,512)
        gemm_lstm<<<dim3(NG / BN, BROWS / BM), dim3(256), 0, stream>>>(
            Xbuf, EMBP, EMBP,
            A2[prv], K2,
            Wc1, Bp1, c1,
            A2[cur], K2, 0,
            (float*)nullptr, 0, K1);

        // layer 2: gates = [h1(t) | h2(t-1)] @ Wc2^T, fused update
        //   whole A from A2[cur] (stride 1024); h2(t) -> A2[prv] cols [512,1024)
        //   final step also writes h2 -> out (fp32)
        gemm_lstm<<<dim3(NG / BN, BROWS / BM), dim3(256), 0, stream>>>(
            (const bf16*)nullptr, 0, 0,
            A2[cur], K2,
            Wc2, Bp2, c2,
            A2[prv], K2, RNN,
            out, (t == TSTEPS - 1) ? 1 : 0, K2);
    }
}

// Round 8
// 1245.123 us; speedup vs baseline: 1.8054x; 1.8054x over previous
//
#include <hip/hip_runtime.h>
#include <hip/hip_bf16.h>

// Problem constants (from reference): B=64, NCLS=200 -> BN rows = 12800
#define BROWS  12800
#define TSTEPS 8
#define EMB    300
#define EMBP   320          // EMB padded to /32, x-slot width
#define RNN    512
#define NG     2048         // 4*RNN gate width
#define K1     832          // EMBP + RNN  (layer-1 concat GEMM K), 13*64
#define K2     1024         // RNN + RNN   (layer-2 concat GEMM K), 16*64

typedef short bf16x8 __attribute__((ext_vector_type(8)));   // 8 bf16 in 4 VGPRs (m89-verified operand type)
typedef float f32x4  __attribute__((ext_vector_type(4)));
typedef __hip_bfloat16 bf16;

__device__ __forceinline__ float sigmoidf_(float x) { return 1.f / (1.f + __expf(-x)); }
// exp-based tanh: exact saturation at +-inf, ~ulp-level error vs tanhf, one v_exp
__device__ __forceinline__ float tanhf_(float x)    { return 1.f - 2.f / (__expf(2.f * x) + 1.f); }

// async global->LDS, 16B per lane (m97). LDS dest = wave-uniform base + lane*16.
__device__ __forceinline__ void gl_lds16(const bf16* g, bf16* l) {
    __builtin_amdgcn_global_load_lds(
        (const __attribute__((address_space(1))) void*)g,
        (__attribute__((address_space(3))) void*)l,
        16, 0, 0);
}

// ---------------------------------------------------------------------------
// Weight repack (round-3 proven): fp32 -> bf16, K-concat LINEAR row-major
// [N=2048][K], GATE-INTERLEAVED row permutation: output row n encodes
//   w = n&15 (unit), g = (n>>4)&3 (gate i,f,g,o), b = n>>6 (unit group)
//   original row = g*512 + b*16 + w
// => each wave's 64-col span = [i|f|g|o] of the same 16 units (epilogue needs
// no cross-lane exchange). Emits permuted combined biases Bp = bih+bhh.
// ---------------------------------------------------------------------------
__global__ void convert_weights(const float* __restrict__ Wih1, const float* __restrict__ Whh1,
                                const float* __restrict__ Wih2, const float* __restrict__ Whh2,
                                const float* __restrict__ bih1, const float* __restrict__ bhh1,
                                const float* __restrict__ bih2, const float* __restrict__ bhh2,
                                bf16* __restrict__ Wc1, bf16* __restrict__ Wc2,
                                float* __restrict__ Bp1, float* __restrict__ Bp2) {
    int idx = blockIdx.x * 256 + threadIdx.x;
    const int n1 = NG * K1;   // 1,703,936
    const int n2 = NG * K2;   // 2,097,152
    if (idx < n1) {
        int n = idx / K1, k = idx - n * K1;
        int on = ((n >> 4) & 3) * RNN + (n >> 6) * 16 + (n & 15);
        float v = 0.f;
        if (k < EMB)        v = Wih1[on * EMB + k];
        else if (k >= EMBP) v = Whh1[on * RNN + (k - EMBP)];
        Wc1[idx] = __float2bfloat16(v);
    }
    if (idx < n2) {
        int n = idx >> 10, k = idx & (K2 - 1);
        int on = ((n >> 4) & 3) * RNN + (n >> 6) * 16 + (n & 15);
        float v = (k < RNN) ? Wih2[on * RNN + k] : Whh2[on * RNN + (k - RNN)];
        Wc2[idx] = __float2bfloat16(v);
    }
    if (idx < NG) {
        int on = ((idx >> 4) & 3) * RNN + (idx >> 6) * 16 + (idx & 15);
        Bp1[idx] = bih1[on] + bhh1[on];
        Bp2[idx] = bih2[on] + bhh2[on];
    }
}

// ---------------------------------------------------------------------------
// Embedding gather + tanh -> Xbuf [BROWS][320] (cols 300..319 zero pad).
// Written before layer-1 reads it each step; nothing else touches it.
// ---------------------------------------------------------------------------
__global__ void embed_step(const int* __restrict__ sent, const float* __restrict__ w2v,
                           bf16* __restrict__ Xbuf, int t) {
    int row = blockIdx.x;
    int col = threadIdx.x;                 // 0..319
    int id  = sent[row * TSTEPS + t];
    float v = (col < EMB) ? tanhf_(w2v[id * EMB + col]) : 0.f;
    Xbuf[(size_t)row * EMBP + col] = __float2bfloat16(v);
}

// ---------------------------------------------------------------------------
// Fused GEMM + LSTM cell update (round-3 core, RACE-FREE dataflow).
//   gates[M,2048] = A[M,K] * W[2048,K]^T  (bf16 MFMA 16x16x32, fp32 acc)
// A is a virtual K-concat of two sources:
//   k <  ksplit : Ax (row stride ldx)      — layer-1 x_t, layer-2 unused
//   k >= ksplit : Ah (row stride ldh_in)   — h columns from the PREVIOUS
//                                            dispatch's buffer (ping-pong)
// The write target hdst is always the OTHER A2 buffer => no dispatch ever
// reads and writes the same buffer (round-6's race is structurally gone).
//
// __launch_bounds__(256,4): 128-reg/thread budget. ROUND-7 LESSON: (256,5)
// caps the unified VGPR/AGPR file at ~102 regs -> spills the 64-reg
// accumulator to scratch -> ~230 MB/dispatch of TCC scratch traffic and 2x
// slowdown. Never bound below the 4x4 f32x4 accumulator's need.
//
// Staging: both operands via global_load_lds w=16 (rounds 4&5 proved direct
// global fragment loads are latency-bound losers). LDS unpadded [128][64]
// with XOR chunk swizzle on the global side (zero bank conflicts, round-3).
// Epilogue: per (row,unit) c'=sig(f)*c+sig(i)*tanh(g); h=sig(o)*tanh(c');
// weight permutation puts gates i,f,g,o of one (row,unit) in one thread.
// h routed through LDS transpose (stride 40, 80B rows, minor 2-way alias)
// for full-line coalesced global stores (round-5: WRITE == ideal).
// Block 256 thr = 4 waves; tile 128x128; wave 64x64 = 4x4 MFMA tiles.
// Grid (16,100), bn fastest => same-bm blocks dispatch-adjacent (L2 sharing
// of A row-slices; round-6 showed breaking this adjacency is costly).
// ---------------------------------------------------------------------------
#define BM 128
#define BN 128

__global__ __launch_bounds__(256, 4) void gemm_lstm(const bf16* __restrict__ Ax, int ldx, int ksplit,
                                                    const bf16* __restrict__ Ah, int ldh_in,
                                                    const bf16* __restrict__ W,
                                                    const float* __restrict__ Bp,
                                                    float* __restrict__ cst,
                                                    bf16* __restrict__ hdst, int ldh_out, int offh,
                                                    float* __restrict__ outf, int en_out,
                                                    int K) {
    __shared__ __attribute__((aligned(16))) bf16 sA[BM * 64];   // 16 KB (reused as h xpose buf)
    __shared__ __attribute__((aligned(16))) bf16 sB[BN * 64];   // 16 KB

    const int tid  = threadIdx.x;
    const int lane = tid & 63;
    const int wave = tid >> 6;
    const int wm   = wave >> 1, wn = wave & 1;
    const int bn   = blockIdx.x;           // 16  (gate-col blocks, fastest)
    const int bm   = blockIdx.y;           // 100 (row blocks)

    f32x4 acc[4][4];
#pragma unroll
    for (int i = 0; i < 4; ++i)
#pragma unroll
        for (int j = 0; j < 4; ++j)
#pragma unroll
            for (int r = 0; r < 4; ++r) acc[i][j][r] = 0.f;

    const int r = lane & 15, q = lane >> 4;

    // staging geometry: chunk ch = c*256+tid; row = ch>>3;
    // global k-chunk = (ch&7)^(row&7)  (XOR swizzle, zero conflicts)
    int srow[4], scol[4];
#pragma unroll
    for (int c = 0; c < 4; ++c) {
        int ch = c * 256 + tid;
        srow[c] = ch >> 3;
        scol[c] = ((ch & 7) ^ (srow[c] & 7)) * 8;
    }
    const bf16* Wbase = W + (size_t)(bn * BN) * K;

    for (int kb = 0; kb < K; kb += 64) {
        // wave-uniform source select (x-region vs h-region of the virtual A)
        const bf16* src; int ld, ko;
        if (kb < ksplit) { src = Ax; ld = ldx;    ko = kb; }
        else             { src = Ah; ld = ldh_in; ko = kb - ksplit; }
        src += (size_t)(bm * BM) * ld;
#pragma unroll
        for (int c = 0; c < 4; ++c) {
            int ch = c * 256 + tid;
            gl_lds16(src   + (size_t)srow[c] * ld + ko + scol[c], &sA[ch * 8]);
            gl_lds16(Wbase + (size_t)srow[c] * K  + kb + scol[c], &sB[ch * 8]);
        }
        __syncthreads();
#pragma unroll
        for (int kk = 0; kk < 64; kk += 32) {
            const int kc = kk >> 3;        // 0 or 4
            bf16x8 af[4], wf[4];
#pragma unroll
            for (int i = 0; i < 4; ++i)
                af[i] = *(const bf16x8*)(&sA[(wm * 64 + i * 16 + r) * 64 + (((q + kc) ^ (r & 7)) * 8)]);
#pragma unroll
            for (int j = 0; j < 4; ++j)
                wf[j] = *(const bf16x8*)(&sB[(wn * 64 + j * 16 + r) * 64 + (((q + kc) ^ (r & 7)) * 8)]);
#pragma unroll
            for (int i = 0; i < 4; ++i)
#pragma unroll
                for (int j = 0; j < 4; ++j)
                    acc[i][j] = __builtin_amdgcn_mfma_f32_16x16x32_bf16(
                        af[i], wf[j], acc[i][j], 0, 0, 0);
        }
        __syncthreads();
    }
    // trailing barrier: all sA reads done -> safe to reuse as h buffer

    // ---- fused LSTM epilogue ----
    // C/D mapping (m89/m91-verified): col = lane&15, row = (lane>>4)*4 + reg
    const int colb = bn * BN + wn * 64;
    const int u    = (2 * bn + wn) * 16 + r;      // global unit index 0..511
    const float bi = Bp[colb + r];
    const float bf = Bp[colb + 16 + r];
    const float bg = Bp[colb + 32 + r];
    const float bo = Bp[colb + 48 + r];

    // hoist the 16 c-loads so their latency overlaps the math below
    float cc[4][4];
#pragma unroll
    for (int i = 0; i < 4; ++i)
#pragma unroll
        for (int rr = 0; rr < 4; ++rr) {
            int row = bm * BM + wm * 64 + i * 16 + q * 4 + rr;
            cc[i][rr] = cst[(size_t)row * RNN + u];
        }

#define HLD 40   // h-xpose row stride: 80B rows (16B-aligned)
#pragma unroll
    for (int i = 0; i < 4; ++i) {
#pragma unroll
        for (int rr = 0; rr < 4; ++rr) {
            int rowl = wm * 64 + i * 16 + q * 4 + rr;       // row in block
            int row  = bm * BM + rowl;
            size_t cidx = (size_t)row * RNN + u;
            float gi = acc[i][0][rr] + bi;
            float gf = acc[i][1][rr] + bf;
            float gg = acc[i][2][rr] + bg;
            float go = acc[i][3][rr] + bo;
            float cn = sigmoidf_(gf) * cc[i][rr] + sigmoidf_(gi) * tanhf_(gg);
            float h  = sigmoidf_(go) * tanhf_(cn);
            cst[cidx] = cn;                                  // 64B segments
            if (en_out) outf[cidx] = h;
            sA[rowl * HLD + wn * 16 + r] = __float2bfloat16(h);
        }
    }
    __syncthreads();

    // coalesced h stores: 128 rows x 32 units bf16; 16B x 512 chunks
#pragma unroll
    for (int half = 0; half < 2; ++half) {
        int t    = half * 256 + tid;       // 0..511
        int rowl = t >> 2;                 // 0..127
        int c8   = (t & 3) * 8;            // 0,8,16,24
        uint4 v  = *(const uint4*)&sA[rowl * HLD + c8];
        int row  = bm * BM + rowl;
        int gcol = bn * 32 + c8;           // unit col within [0,512)
        *(uint4*)&hdst[(size_t)row * ldh_out + offh + gcol] = v;
    }
#undef HLD
}

// ---------------------------------------------------------------------------
// Workspace layout (all 16B-aligned; total 120,668,160 B):
//   c1   fp32 [12800][512]           26,214,400   offset 0
//   c2   fp32 [12800][512]           26,214,400   offset  26,214,400
//   A2a  bf16 [12800][1024]          26,214,400   offset  52,428,800
//   A2b  bf16 [12800][1024]          26,214,400   offset  78,643,200
//   Xbuf bf16 [12800][320]            8,192,000   offset 104,857,600
//   Wc1  bf16 [2048][832]             3,407,872   offset 113,049,600
//   Wc2  bf16 [2048][1024]            4,194,304   offset 116,457,472
//   Bp1  fp32 [2048]                      8,192   offset 120,651,776
//   Bp2  fp32 [2048]                      8,192   offset 120,659,968
// First 104,857,600 B (c1,c2,A2a,A2b) zeroed each call: c(-1)=0, h1(-1)=0
// (A2b cols[0,512) read at t=0), h2(-1)=0 (A2a cols[512,1024) read at t=0).
// Ping-pong: cur = t&1 (A2a at even t). L1(t): reads A2[!cur][0,512)=h1(t-1),
// writes h1(t)->A2[cur][0,512). L2(t): reads A2[cur]=[h1(t)|h2(t-1)], writes
// h2(t)->A2[!cur][512,1024). No dispatch reads and writes the same buffer.
// ---------------------------------------------------------------------------
extern "C" void kernel_launch(void* const* d_in, const int* in_sizes, int n_in,
                              void* d_out, int out_size, void* d_ws, size_t ws_size,
                              hipStream_t stream) {
    (void)in_sizes; (void)n_in; (void)out_size; (void)ws_size;
    const int*   sent = (const int*)d_in[0];
    const float* w2v  = (const float*)d_in[1];
    const float* Wih1 = (const float*)d_in[2];
    const float* Whh1 = (const float*)d_in[3];
    const float* bih1 = (const float*)d_in[4];
    const float* bhh1 = (const float*)d_in[5];
    const float* Wih2 = (const float*)d_in[6];
    const float* Whh2 = (const float*)d_in[7];
    const float* bih2 = (const float*)d_in[8];
    const float* bhh2 = (const float*)d_in[9];
    float* out = (float*)d_out;

    char* ws = (char*)d_ws;
    float* c1   = (float*)(ws);
    float* c2   = (float*)(ws + 26214400);
    bf16*  A2[2];
    A2[0] = (bf16*)(ws + 52428800);
    A2[1] = (bf16*)(ws + 78643200);
    bf16*  Xbuf = (bf16*) (ws + 104857600);
    bf16*  Wc1  = (bf16*) (ws + 113049600);
    bf16*  Wc2  = (bf16*) (ws + 116457472);
    float* Bp1  = (float*)(ws + 120651776);
    float* Bp2  = (float*)(ws + 120659968);

    // zero c1,c2,A2a,A2b (ws is re-poisoned 0xAA before every call)
    hipMemsetAsync(ws, 0, 104857600, stream);

    convert_weights<<<dim3((NG * K2 + 255) / 256), dim3(256), 0, stream>>>(
        Wih1, Whh1, Wih2, Whh2, bih1, bhh1, bih2, bhh2, Wc1, Wc2, Bp1, Bp2);

    for (int t = 0; t < TSTEPS; ++t) {
        const int cur = t & 1, prv = cur ^ 1;

        // x_t -> Xbuf (cols 300..319 zeroed)
        embed_step<<<dim3(BROWS), dim3(EMBP), 0, stream>>>(sent, w2v, Xbuf, t);

        // layer 1: gates = [x_t | h1(t-1)] @ Wc1^T, fused update
        //   x from Xbuf (stride 320), h1(t-1) from A2[prv] cols [0,512)
        //   h1(t) -> A2[cur] cols [0,512)
        gemm_lstm<<<dim3(NG / BN, BROWS / BM), dim3(256), 0, stream>>>(
            Xbuf, EMBP, EMBP,
            A2[prv], K2,
            Wc1, Bp1, c1,
            A2[cur], K2, 0,
            (float*)nullptr, 0, K1);

        // layer 2: gates = [h1(t) | h2(t-1)] @ Wc2^T, fused update
        //   whole A from A2[cur] (stride 1024); h2(t) -> A2[prv] cols [512,1024)
        //   final step also writes h2 -> out (fp32)
        gemm_lstm<<<dim3(NG / BN, BROWS / BM), dim3(256), 0, stream>>>(
            (const bf16*)nullptr, 0, 0,
            A2[cur], K2,
            Wc2, Bp2, c2,
            A2[prv], K2, RNN,
            out, (t == TSTEPS - 1) ? 1 : 0, K2);
    }
}